// Round 7
// baseline (98.530 us; speedup 1.0000x reference)
//
#include <hip/hip_runtime.h>

// GraphProposalNetwork on MI355X — round 7.
// Algebra: feat=x@Wp+bp is linear into W1 and pair=[vi,vj], so
//   h1[b,i,j,:] = lrelu(g_a[b,i,:] + g_b[b,j,:]) with per-node g = x@(Wp@W1half)+bias.
// Round-7: phase C iterates j in NATURAL order so all lanes read the same
// per-graph row simultaneously -> LDS same-address broadcast (<=2-way conflict,
// free) instead of the 8-way conflicts of the c-permuted order. The c-column
// permutation moves to the store address. Everything else kept from R6.

typedef float v2f __attribute__((ext_vector_type(2)));
typedef float v4f __attribute__((ext_vector_type(4)));

constexpr int G = 12;            // graphs per block (120 of 128 lanes active)
constexpr int GB_STRIDE = 36;    // floats per gb row: 32 + 4 pad (16B aligned)
constexpr float NEG = 0.2f;

// ---- pre-kernel: M = Wp@[W1a|W1b] (3x64) at ws[0..191], c at ws[192..255] ----
__global__ __launch_bounds__(256, 1) void fuse_kernel(
    const float* __restrict__ Wp, const float* __restrict__ bp,
    const float* __restrict__ W1, const float* __restrict__ b1,
    float* __restrict__ ws)
{
    const int t = threadIdx.x;
    if (t < 192) {
        const int d = t >> 6, k = t & 63;
        const int kk = k & 31;
        const int fo = (k < 32) ? 0 : 16;
        float acc = 0.f;
#pragma unroll
        for (int f = 0; f < 16; ++f)
            acc = fmaf(Wp[d * 16 + f], W1[(fo + f) * 32 + kk], acc);
        ws[d * 64 + k] = acc;
    } else {
        const int k = t - 192;
        const int kk = k & 31;
        const int fo = (k < 32) ? 0 : 16;
        float acc = 0.f;
#pragma unroll
        for (int f = 0; f < 16; ++f)
            acc = fmaf(bp[f], W1[(fo + f) * 32 + kk], acc);
        if (k < 32) acc += b1[k];
        ws[192 + k] = acc;
    }
}

__global__ __launch_bounds__(128, 3) void gpn_kernel(
    const float* __restrict__ pos,  // (B,10,2)
    const float* __restrict__ ori,  // (B,10,1)
    const float* __restrict__ ws,   // fused M (192) ++ c (64)
    const float* __restrict__ W2,   // (32,8)
    const float* __restrict__ b2,   // (8)
    const float* __restrict__ W3,   // (8,2)
    const float* __restrict__ b3,   // (2)
    float* __restrict__ out,        // big_edge (B*100*2) ++ adjacency (B*100)
    int B)
{
    __shared__ float sgb[G * 10 * GB_STRIDE]; // per-node g_b halves (17.3 KB)

    const int t = threadIdx.x;
    const int bBase = blockIdx.x * G;
    const int remG = B - bBase;
    const int nRows = ((remG < G) ? remG : G) * 10;

    const v4f* m4 = (const v4f*)ws;          // 48 v4f (3 rows x 16)
    const v4f* c4 = (const v4f*)(ws + 192);  // 16 v4f

    // ---- Phase B: lane owns row r=(g,i); a-half (k<32) in registers,
    // b-half (k>=32) to LDS. M/c reads are wave-uniform -> s_load. ----
    v4f ga[8];
    const int r = t;
    const int g = r / 10;
    const int i = r - g * 10;
    if (r < nRows) {
        const int node = bBase * 10 + r;
        const v2f p = ((const v2f*)pos)[node];
        const float o = ori[node];
        v4f* dst = (v4f*)&sgb[r * GB_STRIDE];
#pragma unroll
        for (int q = 0; q < 8; ++q) {
            v4f gg = c4[q];
            gg += p.x * m4[q];
            gg += p.y * m4[16 + q];
            gg += o   * m4[32 + q];
            ga[q] = gg;
        }
#pragma unroll
        for (int q = 8; q < 16; ++q) {
            v4f gg = c4[q];
            gg += p.x * m4[q];
            gg += p.y * m4[16 + q];
            gg += o   * m4[32 + q];
            dst[q - 8] = gg;
        }
    }
    __syncthreads();

    // ---- Phase C: K-sliced layer 2, j iterated in NATURAL order so a whole
    // wave reads row (g,j) together -> LDS broadcast, ~no bank conflicts. ----
    if (r < nRows) {
        const v2f* w2p = (const v2f*)W2;  // row k: pairs [4k..4k+3]
        const v2f* w3p = (const v2f*)W3;
        const v2f bb2_0 = ((const v2f*)b2)[0];
        const v2f bb2_1 = ((const v2f*)b2)[1];
        const v2f bb2_2 = ((const v2f*)b2)[2];
        const v2f bb2_3 = ((const v2f*)b2)[3];
        const v2f bb3   = ((const v2f*)b3)[0];

        const float* gbase = &sgb[(g * 10) * GB_STRIDE];

        v2f A[10][4];
#pragma unroll
        for (int j = 0; j < 10; ++j) {
            A[j][0] = bb2_0; A[j][1] = bb2_1; A[j][2] = bb2_2; A[j][3] = bb2_3;
        }

#pragma unroll
        for (int q = 0; q < 8; ++q) {
            const v4f gaq = ga[q];
            const int k0 = 4 * q;
            const v2f w00 = w2p[4 * (k0 + 0) + 0], w01 = w2p[4 * (k0 + 0) + 1],
                      w02 = w2p[4 * (k0 + 0) + 2], w03 = w2p[4 * (k0 + 0) + 3];
            const v2f w10 = w2p[4 * (k0 + 1) + 0], w11 = w2p[4 * (k0 + 1) + 1],
                      w12 = w2p[4 * (k0 + 1) + 2], w13 = w2p[4 * (k0 + 1) + 3];
            const v2f w20 = w2p[4 * (k0 + 2) + 0], w21 = w2p[4 * (k0 + 2) + 1],
                      w22 = w2p[4 * (k0 + 2) + 2], w23 = w2p[4 * (k0 + 2) + 3];
            const v2f w30 = w2p[4 * (k0 + 3) + 0], w31 = w2p[4 * (k0 + 3) + 1],
                      w32 = w2p[4 * (k0 + 3) + 2], w33 = w2p[4 * (k0 + 3) + 3];
#pragma unroll
            for (int j = 0; j < 10; ++j) {
                const v4f gb = *(const v4f*)(gbase + j * GB_STRIDE + 4 * q);
                const v4f s = gaq + gb;
                const v4f h = __builtin_elementwise_max(s, s * NEG);
                A[j][0] += h.x * w00; A[j][1] += h.x * w01;
                A[j][2] += h.x * w02; A[j][3] += h.x * w03;
                A[j][0] += h.y * w10; A[j][1] += h.y * w11;
                A[j][2] += h.y * w12; A[j][3] += h.y * w13;
                A[j][0] += h.z * w20; A[j][1] += h.z * w21;
                A[j][2] += h.z * w22; A[j][3] += h.z * w23;
                A[j][0] += h.w * w30; A[j][1] += h.w * w31;
                A[j][2] += h.w * w32; A[j][3] += h.w * w33;
            }
        }

        // ---- layer 3 + immediate stores at permuted column c(j) ----
        const int eRow = (bBase + g) * 100 + i * 10;   // first edge of row
        const size_t adjOff = (size_t)B * 200;
#pragma unroll
        for (int j = 0; j < 10; ++j) {
            const v2f h20 = __builtin_elementwise_max(A[j][0], A[j][0] * NEG);
            const v2f h21 = __builtin_elementwise_max(A[j][1], A[j][1] * NEG);
            const v2f h22 = __builtin_elementwise_max(A[j][2], A[j][2] * NEG);
            const v2f h23 = __builtin_elementwise_max(A[j][3], A[j][3] * NEG);

            v2f ev = bb3;
            ev += h20.x * w3p[0];
            ev += h20.y * w3p[1];
            ev += h21.x * w3p[2];
            ev += h21.y * w3p[3];
            ev += h22.x * w3p[4];
            ev += h22.y * w3p[5];
            ev += h23.x * w3p[6];
            ev += h23.y * w3p[7];

            // column where pair (i, j) lands: c=0 for j==i; j<i -> j+1; j>i -> j
            const int c = (j == i) ? 0 : ((j < i) ? (j + 1) : j);
            const int E = eRow + c;
            ((v2f*)out)[E] = ev;
            out[adjOff + E] = (ev.y > ev.x) ? 1.0f : 0.0f;
        }
    }
}

extern "C" void kernel_launch(void* const* d_in, const int* in_sizes, int n_in,
                              void* d_out, int out_size, void* d_ws, size_t ws_size,
                              hipStream_t stream) {
    const float* pos = (const float*)d_in[0];
    const float* ori = (const float*)d_in[1];
    const float* Wp  = (const float*)d_in[2];
    const float* bp  = (const float*)d_in[3];
    const float* W1  = (const float*)d_in[4];
    const float* b1  = (const float*)d_in[5];
    const float* W2  = (const float*)d_in[6];
    const float* b2  = (const float*)d_in[7];
    const float* W3  = (const float*)d_in[8];
    const float* b3  = (const float*)d_in[9];
    float* out = (float*)d_out;
    float* ws  = (float*)d_ws;

    const int B = in_sizes[0] / 20;           // 16384
    const int nBlocks = (B + G - 1) / G;      // 1366

    fuse_kernel<<<1, 256, 0, stream>>>(Wp, bp, W1, b1, ws);
    gpn_kernel<<<nBlocks, 128, 0, stream>>>(pos, ori, ws, W2, b2, W3, b3, out, B);
}

// Round 8
// 94.947 us; speedup vs baseline: 1.0377x; 1.0377x over previous
//
#include <hip/hip_runtime.h>

// GraphProposalNetwork on MI355X — round 8.
// Algebra: feat=x@Wp+bp is linear into W1 and pair=[vi,vj], so
//   h1[b,i,j,:] = lrelu(g_a[b,i,:] + g_b[b,j,:]) with per-node g = x@(Wp@W1half)+bias.
// Round-8: store-path experiment. Results staged to LDS (overlaid on sgb) and
// written as fully-coalesced, full-cache-line dwordx4 NON-TEMPORAL stores (no
// LLC allocate -> no dirty-line eviction storm from the harness's 268MB 0xAA
// ws-poison fill; zero partial-line RMW). Compute phases kept from R7.

typedef float v2f __attribute__((ext_vector_type(2)));
typedef float v4f __attribute__((ext_vector_type(4)));

constexpr int G = 24;            // graphs per block (240 of 256 lanes active)
constexpr int GB_STRIDE = 36;    // floats per gb row: 32 + 4 pad (16B aligned)
constexpr float NEG = 0.2f;

// LDS: phase B/C uses sgb (240*36 = 8640 floats); epilogue overlays results
// (4800 big_edge + 2400 adj = 7200 floats) on the same storage.
constexpr int SGB_FLOATS = G * 10 * GB_STRIDE;   // 8640
constexpr int RES_E_FLOATS = G * 200;            // 4800
constexpr int RES_A_FLOATS = G * 100;            // 2400

// ---- pre-kernel: M = Wp@[W1a|W1b] (3x64) at ws[0..191], c at ws[192..255] ----
__global__ __launch_bounds__(256, 1) void fuse_kernel(
    const float* __restrict__ Wp, const float* __restrict__ bp,
    const float* __restrict__ W1, const float* __restrict__ b1,
    float* __restrict__ ws)
{
    const int t = threadIdx.x;
    if (t < 192) {
        const int d = t >> 6, k = t & 63;
        const int kk = k & 31;
        const int fo = (k < 32) ? 0 : 16;
        float acc = 0.f;
#pragma unroll
        for (int f = 0; f < 16; ++f)
            acc = fmaf(Wp[d * 16 + f], W1[(fo + f) * 32 + kk], acc);
        ws[d * 64 + k] = acc;
    } else {
        const int k = t - 192;
        const int kk = k & 31;
        const int fo = (k < 32) ? 0 : 16;
        float acc = 0.f;
#pragma unroll
        for (int f = 0; f < 16; ++f)
            acc = fmaf(bp[f], W1[(fo + f) * 32 + kk], acc);
        if (k < 32) acc += b1[k];
        ws[192 + k] = acc;
    }
}

__global__ __launch_bounds__(256, 2) void gpn_kernel(
    const float* __restrict__ pos,  // (B,10,2)
    const float* __restrict__ ori,  // (B,10,1)
    const float* __restrict__ ws,   // fused M (192) ++ c (64)
    const float* __restrict__ W2,   // (32,8)
    const float* __restrict__ b2,   // (8)
    const float* __restrict__ W3,   // (8,2)
    const float* __restrict__ b3,   // (2)
    float* __restrict__ out,        // big_edge (B*100*2) ++ adjacency (B*100)
    int B)
{
    __shared__ float sL[SGB_FLOATS];   // sgb, later overlaid with results

    const int t = threadIdx.x;
    const int bBase = blockIdx.x * G;
    const int remG0 = B - bBase;
    const int remG = (remG0 < G) ? remG0 : G;
    const int nRows = remG * 10;

    const v4f* m4 = (const v4f*)ws;          // 48 v4f (3 rows x 16)
    const v4f* c4 = (const v4f*)(ws + 192);  // 16 v4f

    // ---- Phase B: lane owns row r=(g,i); a-half (k<32) in registers,
    // b-half (k>=32) to LDS. ----
    v4f ga[8];
    const int r = t;
    const int g = r / 10;
    const int i = r - g * 10;
    if (r < nRows) {
        const int node = bBase * 10 + r;
        const v2f p = ((const v2f*)pos)[node];
        const float o = ori[node];
        v4f* dst = (v4f*)&sL[r * GB_STRIDE];
#pragma unroll
        for (int q = 0; q < 8; ++q) {
            v4f gg = c4[q];
            gg += p.x * m4[q];
            gg += p.y * m4[16 + q];
            gg += o   * m4[32 + q];
            ga[q] = gg;
        }
#pragma unroll
        for (int q = 8; q < 16; ++q) {
            v4f gg = c4[q];
            gg += p.x * m4[q];
            gg += p.y * m4[16 + q];
            gg += o   * m4[32 + q];
            dst[q - 8] = gg;
        }
    }
    __syncthreads();

    // ---- Phase C: K-sliced layer 2, j in natural order (wave-broadcast LDS
    // reads, zero bank conflicts — verified R7). ----
    v2f A[10][4];
    if (r < nRows) {
        const v2f* w2p = (const v2f*)W2;
        const v2f bb2_0 = ((const v2f*)b2)[0];
        const v2f bb2_1 = ((const v2f*)b2)[1];
        const v2f bb2_2 = ((const v2f*)b2)[2];
        const v2f bb2_3 = ((const v2f*)b2)[3];

        const float* gbase = &sL[(g * 10) * GB_STRIDE];

#pragma unroll
        for (int j = 0; j < 10; ++j) {
            A[j][0] = bb2_0; A[j][1] = bb2_1; A[j][2] = bb2_2; A[j][3] = bb2_3;
        }

#pragma unroll
        for (int q = 0; q < 8; ++q) {
            const v4f gaq = ga[q];
            const int k0 = 4 * q;
            const v2f w00 = w2p[4 * (k0 + 0) + 0], w01 = w2p[4 * (k0 + 0) + 1],
                      w02 = w2p[4 * (k0 + 0) + 2], w03 = w2p[4 * (k0 + 0) + 3];
            const v2f w10 = w2p[4 * (k0 + 1) + 0], w11 = w2p[4 * (k0 + 1) + 1],
                      w12 = w2p[4 * (k0 + 1) + 2], w13 = w2p[4 * (k0 + 1) + 3];
            const v2f w20 = w2p[4 * (k0 + 2) + 0], w21 = w2p[4 * (k0 + 2) + 1],
                      w22 = w2p[4 * (k0 + 2) + 2], w23 = w2p[4 * (k0 + 2) + 3];
            const v2f w30 = w2p[4 * (k0 + 3) + 0], w31 = w2p[4 * (k0 + 3) + 1],
                      w32 = w2p[4 * (k0 + 3) + 2], w33 = w2p[4 * (k0 + 3) + 3];
#pragma unroll
            for (int j = 0; j < 10; ++j) {
                const v4f gb = *(const v4f*)(gbase + j * GB_STRIDE + 4 * q);
                const v4f s = gaq + gb;
                const v4f h = __builtin_elementwise_max(s, s * NEG);
                A[j][0] += h.x * w00; A[j][1] += h.x * w01;
                A[j][2] += h.x * w02; A[j][3] += h.x * w03;
                A[j][0] += h.y * w10; A[j][1] += h.y * w11;
                A[j][2] += h.y * w12; A[j][3] += h.y * w13;
                A[j][0] += h.z * w20; A[j][1] += h.z * w21;
                A[j][2] += h.z * w22; A[j][3] += h.z * w23;
                A[j][0] += h.w * w30; A[j][1] += h.w * w31;
                A[j][2] += h.w * w32; A[j][3] += h.w * w33;
            }
        }
    }
    __syncthreads();   // all sgb reads done; safe to overlay results

    // ---- layer 3; results into LDS at permuted column c(j) ----
    float* res_e = sL;                    // [G*200] big_edge, block-flat
    float* res_a = sL + RES_E_FLOATS;     // [G*100] adjacency
    if (r < nRows) {
        const v2f* w3p = (const v2f*)W3;
        const v2f bb3 = ((const v2f*)b3)[0];
#pragma unroll
        for (int j = 0; j < 10; ++j) {
            const v2f h20 = __builtin_elementwise_max(A[j][0], A[j][0] * NEG);
            const v2f h21 = __builtin_elementwise_max(A[j][1], A[j][1] * NEG);
            const v2f h22 = __builtin_elementwise_max(A[j][2], A[j][2] * NEG);
            const v2f h23 = __builtin_elementwise_max(A[j][3], A[j][3] * NEG);

            v2f ev = bb3;
            ev += h20.x * w3p[0];
            ev += h20.y * w3p[1];
            ev += h21.x * w3p[2];
            ev += h21.y * w3p[3];
            ev += h22.x * w3p[4];
            ev += h22.y * w3p[5];
            ev += h23.x * w3p[6];
            ev += h23.y * w3p[7];

            const int c = (j == i) ? 0 : ((j < i) ? (j + 1) : j);
            const int eIdx = r * 10 + c;            // (g*10+i)*10+c
            *(v2f*)&res_e[eIdx * 2] = ev;           // ds_write_b64
            res_a[eIdx] = (ev.y > ev.x) ? 1.0f : 0.0f;
        }
    }
    __syncthreads();

    // ---- coalesced full-line non-temporal stores ----
    {
        const int nV4e = remG * 50;                 // big_edge v4f count
        const v4f* se = (const v4f*)res_e;
        v4f* oe = (v4f*)(out + (size_t)bBase * 200);
        for (int idx = t; idx < nV4e; idx += 256)
            __builtin_nontemporal_store(se[idx], &oe[idx]);

        const int nV4a = remG * 25;                 // adjacency v4f count
        const v4f* sa = (const v4f*)res_a;
        v4f* oa = (v4f*)(out + (size_t)B * 200 + (size_t)bBase * 100);
        for (int idx = t; idx < nV4a; idx += 256)
            __builtin_nontemporal_store(sa[idx], &oa[idx]);
    }
}

extern "C" void kernel_launch(void* const* d_in, const int* in_sizes, int n_in,
                              void* d_out, int out_size, void* d_ws, size_t ws_size,
                              hipStream_t stream) {
    const float* pos = (const float*)d_in[0];
    const float* ori = (const float*)d_in[1];
    const float* Wp  = (const float*)d_in[2];
    const float* bp  = (const float*)d_in[3];
    const float* W1  = (const float*)d_in[4];
    const float* b1  = (const float*)d_in[5];
    const float* W2  = (const float*)d_in[6];
    const float* b2  = (const float*)d_in[7];
    const float* W3  = (const float*)d_in[8];
    const float* b3  = (const float*)d_in[9];
    float* out = (float*)d_out;
    float* ws  = (float*)d_ws;

    const int B = in_sizes[0] / 20;           // 16384
    const int nBlocks = (B + G - 1) / G;      // 683

    fuse_kernel<<<1, 256, 0, stream>>>(Wp, bp, W1, b1, ws);
    gpn_kernel<<<nBlocks, 256, 0, stream>>>(pos, ori, ws, W2, b2, W3, b3, out, B);
}

// Round 9
// 94.258 us; speedup vs baseline: 1.0453x; 1.0073x over previous
//
#include <hip/hip_runtime.h>

// GraphProposalNetwork on MI355X — round 9.
// Algebra: feat=x@Wp+bp is linear into W1 and pair=[vi,vj], so
//   h1[b,i,j,:] = lrelu(g_a[b,i,:] + g_b[b,j,:]) with per-node g = x@(Wp@W1half)+bias.
// Round-9: SINGLE kernel. The serial 1-block fuse pre-kernel is gone — every
// block computes M=Wp@[W1a|W1b] + bias c into its own LDS (~3K MACs, overlapped
// across 683 blocks). Per-lane pos/ori loads are issued FIRST so their cold-miss
// latency hides under phase-A math. Phases B/C + coalesced NT epilogue from R8.

typedef float v2f __attribute__((ext_vector_type(2)));
typedef float v4f __attribute__((ext_vector_type(4)));

constexpr int G = 24;            // graphs per block (240 of 256 lanes active)
constexpr int GB_STRIDE = 36;    // floats per gb row: 32 + 4 pad (16B aligned)
constexpr float NEG = 0.2f;

constexpr int SGB_FLOATS = G * 10 * GB_STRIDE;   // 8640; epilogue overlays 7200
constexpr int RES_E_FLOATS = G * 200;            // 4800

__global__ __launch_bounds__(256, 2) void gpn_kernel(
    const float* __restrict__ pos,  // (B,10,2)
    const float* __restrict__ ori,  // (B,10,1)
    const float* __restrict__ Wp,   // (3,16)
    const float* __restrict__ bp,   // (16)
    const float* __restrict__ W1,   // (32,32)
    const float* __restrict__ b1,   // (32)
    const float* __restrict__ W2,   // (32,8)
    const float* __restrict__ b2,   // (8)
    const float* __restrict__ W3,   // (8,2)
    const float* __restrict__ b3,   // (2)
    float* __restrict__ out,        // big_edge (B*100*2) ++ adjacency (B*100)
    int B)
{
    __shared__ float sL[SGB_FLOATS];   // gb rows; later overlaid with results
    __shared__ float sM[3 * 64];       // fused Wp@[W1a|W1b]
    __shared__ float sc[64];           // fused bias (b1 folded into first 32)

    const int t = threadIdx.x;
    const int bBase = blockIdx.x * G;
    const int remG0 = B - bBase;
    const int remG = (remG0 < G) ? remG0 : G;
    const int nRows = remG * 10;

    const int r = t;
    const int g = r / 10;
    const int i = r - g * 10;

    // ---- issue this lane's node loads FIRST (latency overlaps phase A) ----
    v2f p = {0.f, 0.f};
    float o = 0.f;
    if (r < nRows) {
        const int node = bBase * 10 + r;
        p = ((const v2f*)pos)[node];
        o = ori[node];
    }

    // ---- Phase A (per-block): M = Wp@[W1a|W1b] (3x64), c = bp@[.] (+b1) ----
    if (t < 192) {
        const int d = t >> 6, k = t & 63;
        const int kk = k & 31;
        const int fo = (k < 32) ? 0 : 16;
        float acc = 0.f;
#pragma unroll
        for (int f = 0; f < 16; ++f)
            acc = fmaf(Wp[d * 16 + f], W1[(fo + f) * 32 + kk], acc);
        sM[d * 64 + k] = acc;
    } else {
        const int k = t - 192;
        const int kk = k & 31;
        const int fo = (k < 32) ? 0 : 16;
        float acc = 0.f;
#pragma unroll
        for (int f = 0; f < 16; ++f)
            acc = fmaf(bp[f], W1[(fo + f) * 32 + kk], acc);
        if (k < 32) acc += b1[k];
        sc[k] = acc;
    }
    __syncthreads();

    // ---- Phase B: lane owns row r=(g,i); a-half (k<32) in registers,
    // b-half (k>=32) to LDS. sM/sc reads are same-address broadcast. ----
    v4f ga[8];
    if (r < nRows) {
        const v4f* m4 = (const v4f*)sM;   // 48 v4f
        const v4f* c4 = (const v4f*)sc;   // 16 v4f
        v4f* dst = (v4f*)&sL[r * GB_STRIDE];
#pragma unroll
        for (int q = 0; q < 8; ++q) {
            v4f gg = c4[q];
            gg += p.x * m4[q];
            gg += p.y * m4[16 + q];
            gg += o   * m4[32 + q];
            ga[q] = gg;
        }
#pragma unroll
        for (int q = 8; q < 16; ++q) {
            v4f gg = c4[q];
            gg += p.x * m4[q];
            gg += p.y * m4[16 + q];
            gg += o   * m4[32 + q];
            dst[q - 8] = gg;
        }
    }
    __syncthreads();

    // ---- Phase C: K-sliced layer 2, j in natural order (wave-broadcast LDS
    // reads, zero bank conflicts — verified R7). W2 via wave-uniform s_load. ----
    v2f A[10][4];
    if (r < nRows) {
        const v2f* w2p = (const v2f*)W2;
        const v2f bb2_0 = ((const v2f*)b2)[0];
        const v2f bb2_1 = ((const v2f*)b2)[1];
        const v2f bb2_2 = ((const v2f*)b2)[2];
        const v2f bb2_3 = ((const v2f*)b2)[3];

        const float* gbase = &sL[(g * 10) * GB_STRIDE];

#pragma unroll
        for (int j = 0; j < 10; ++j) {
            A[j][0] = bb2_0; A[j][1] = bb2_1; A[j][2] = bb2_2; A[j][3] = bb2_3;
        }

#pragma unroll
        for (int q = 0; q < 8; ++q) {
            const v4f gaq = ga[q];
            const int k0 = 4 * q;
            const v2f w00 = w2p[4 * (k0 + 0) + 0], w01 = w2p[4 * (k0 + 0) + 1],
                      w02 = w2p[4 * (k0 + 0) + 2], w03 = w2p[4 * (k0 + 0) + 3];
            const v2f w10 = w2p[4 * (k0 + 1) + 0], w11 = w2p[4 * (k0 + 1) + 1],
                      w12 = w2p[4 * (k0 + 1) + 2], w13 = w2p[4 * (k0 + 1) + 3];
            const v2f w20 = w2p[4 * (k0 + 2) + 0], w21 = w2p[4 * (k0 + 2) + 1],
                      w22 = w2p[4 * (k0 + 2) + 2], w23 = w2p[4 * (k0 + 2) + 3];
            const v2f w30 = w2p[4 * (k0 + 3) + 0], w31 = w2p[4 * (k0 + 3) + 1],
                      w32 = w2p[4 * (k0 + 3) + 2], w33 = w2p[4 * (k0 + 3) + 3];
#pragma unroll
            for (int j = 0; j < 10; ++j) {
                const v4f gb = *(const v4f*)(gbase + j * GB_STRIDE + 4 * q);
                const v4f s = gaq + gb;
                const v4f h = __builtin_elementwise_max(s, s * NEG);
                A[j][0] += h.x * w00; A[j][1] += h.x * w01;
                A[j][2] += h.x * w02; A[j][3] += h.x * w03;
                A[j][0] += h.y * w10; A[j][1] += h.y * w11;
                A[j][2] += h.y * w12; A[j][3] += h.y * w13;
                A[j][0] += h.z * w20; A[j][1] += h.z * w21;
                A[j][2] += h.z * w22; A[j][3] += h.z * w23;
                A[j][0] += h.w * w30; A[j][1] += h.w * w31;
                A[j][2] += h.w * w32; A[j][3] += h.w * w33;
            }
        }
    }
    __syncthreads();   // all sL reads done; safe to overlay results

    // ---- layer 3; results into LDS at permuted column c(j) ----
    float* res_e = sL;                    // [G*200] big_edge, block-flat
    float* res_a = sL + RES_E_FLOATS;     // [G*100] adjacency
    if (r < nRows) {
        const v2f* w3p = (const v2f*)W3;
        const v2f bb3 = ((const v2f*)b3)[0];
#pragma unroll
        for (int j = 0; j < 10; ++j) {
            const v2f h20 = __builtin_elementwise_max(A[j][0], A[j][0] * NEG);
            const v2f h21 = __builtin_elementwise_max(A[j][1], A[j][1] * NEG);
            const v2f h22 = __builtin_elementwise_max(A[j][2], A[j][2] * NEG);
            const v2f h23 = __builtin_elementwise_max(A[j][3], A[j][3] * NEG);

            v2f ev = bb3;
            ev += h20.x * w3p[0];
            ev += h20.y * w3p[1];
            ev += h21.x * w3p[2];
            ev += h21.y * w3p[3];
            ev += h22.x * w3p[4];
            ev += h22.y * w3p[5];
            ev += h23.x * w3p[6];
            ev += h23.y * w3p[7];

            const int c = (j == i) ? 0 : ((j < i) ? (j + 1) : j);
            const int eIdx = r * 10 + c;            // (g*10+i)*10+c
            *(v2f*)&res_e[eIdx * 2] = ev;           // ds_write_b64
            res_a[eIdx] = (ev.y > ev.x) ? 1.0f : 0.0f;
        }
    }
    __syncthreads();

    // ---- coalesced full-line non-temporal stores ----
    {
        const int nV4e = remG * 50;                 // big_edge v4f count
        const v4f* se = (const v4f*)res_e;
        v4f* oe = (v4f*)(out + (size_t)bBase * 200);
        for (int idx = t; idx < nV4e; idx += 256)
            __builtin_nontemporal_store(se[idx], &oe[idx]);

        const int nV4a = remG * 25;                 // adjacency v4f count
        const v4f* sa = (const v4f*)res_a;
        v4f* oa = (v4f*)(out + (size_t)B * 200 + (size_t)bBase * 100);
        for (int idx = t; idx < nV4a; idx += 256)
            __builtin_nontemporal_store(sa[idx], &oa[idx]);
    }
}

extern "C" void kernel_launch(void* const* d_in, const int* in_sizes, int n_in,
                              void* d_out, int out_size, void* d_ws, size_t ws_size,
                              hipStream_t stream) {
    const float* pos = (const float*)d_in[0];
    const float* ori = (const float*)d_in[1];
    const float* Wp  = (const float*)d_in[2];
    const float* bp  = (const float*)d_in[3];
    const float* W1  = (const float*)d_in[4];
    const float* b1  = (const float*)d_in[5];
    const float* W2  = (const float*)d_in[6];
    const float* b2  = (const float*)d_in[7];
    const float* W3  = (const float*)d_in[8];
    const float* b3  = (const float*)d_in[9];
    float* out = (float*)d_out;

    const int B = in_sizes[0] / 20;           // 16384
    const int nBlocks = (B + G - 1) / G;      // 683

    gpn_kernel<<<nBlocks, 256, 0, stream>>>(pos, ori, Wp, bp, W1, b1, W2, b2,
                                            W3, b3, out, B);
}